// Round 1
// 1605.357 us; speedup vs baseline: 1.0607x; 1.0607x over previous
//
#include <hip/hip_runtime.h>
#include <hip/hip_bf16.h>

typedef __attribute__((ext_vector_type(4))) float  floatx4;
typedef __attribute__((ext_vector_type(8))) short  shortx8;
typedef __attribute__((ext_vector_type(4))) short  shortx4;

__device__ __forceinline__ short f2bf(float x) {
    union { float f; unsigned u; } v; v.f = x;
    unsigned r = v.u + 0x7FFFu + ((v.u >> 16) & 1u);   // round-to-nearest-even
    return (short)(r >> 16);
}
__device__ __forceinline__ float bf2f(short x) {
    union { unsigned u; float f; } c; c.u = ((unsigned)(unsigned short)x) << 16;
    return c.f;
}
// hardware RNE f32->bf16 (compiler emits v_cvt_pk_bf16_f32; same rounding as f2bf)
__device__ __forceinline__ short f2bf_hw(float x) {
    union { __hip_bfloat16 h; short s; } u;
    u.h = __float2bfloat16(x);
    return u.s;
}

// async global->LDS, 16 B per lane; LDS dest must be wave-uniform base + lane*16
__device__ __forceinline__ void gload16(const void* g, void* l) {
    __builtin_amdgcn_global_load_lds(
        (const __attribute__((address_space(1))) void*)g,
        (__attribute__((address_space(3))) void*)l, 16, 0, 0);
}

// ---------------- prep kernels ----------------

__global__ void cast_bf16(const float* __restrict__ src, short* __restrict__ dst, int n4) {
    int i = blockIdx.x * blockDim.x + threadIdx.x;
    if (i < n4) {
        floatx4 v = ((const floatx4*)src)[i];
        shortx4 s;
        s[0] = f2bf(v[0]); s[1] = f2bf(v[1]); s[2] = f2bf(v[2]); s[3] = f2bf(v[3]);
        ((shortx4*)dst)[i] = s;
    }
}

// dst[c][r] = (bf16)src[r][c], per-z batch. src: R x C fp32. dst: C x R bf16.
__global__ void transpose_cast(const float* __restrict__ src, short* __restrict__ dst,
                               int R, int C, long szSrc, long szDst) {
    __shared__ float tile[32][33];
    const float* s = src + (long)blockIdx.z * szSrc;
    short* d = dst + (long)blockIdx.z * szDst;
    int c0 = blockIdx.x * 32, r0 = blockIdx.y * 32;
    for (int i = threadIdx.y; i < 32; i += 8)
        tile[i][threadIdx.x] = s[(long)(r0 + i) * C + c0 + threadIdx.x];
    __syncthreads();
    for (int i = threadIdx.y; i < 32; i += 8)
        d[(long)(c0 + i) * R + r0 + threadIdx.x] = f2bf(tile[threadIdx.x][i]);
}

// ---------------- NT GEMM: C[M,N] = A[M,K] * B[N,K]^T ----------------
// m97-style structure: 128x128 tile, BK=32, 256 threads = 4 waves (2x2),
// 4x4 mfma 16x16x32 per wave, staging via global_load_lds width=16 (async,
// no VGPR round-trip). LDS is LINEAR (global_load_lds requires it); bank
// conflicts on the fragment ds_read_b128 are avoided by XOR-swizzling the
// *global source column* at stage time and applying the same involution on
// the read side (rule #21: both-sides-or-neither):
//   bf16 tiles (64 B rows, 4x 16B slots):  slot ^= (row>>1)&3   -> 2-way (free)
//   fp32 A tile (128 B rows, 8x 16B slots): slot ^= row&7       -> 2-way (free)
// AF32: A stays fp32 in LDS; converted to bf16 at fragment read with the
// hardware cvt (v_cvt_pk_bf16_f32), RNE like before.
// XSWZ (grid must be (8,32,4)): bijective remap so the 8 n-blocks sharing one
// A-panel land on one XCD (XCD = dispatch_index % 8) -> A-panel hits L2 once.
// aHX: extra element offset added per 4096 of block-local k (per-head layout).

#define BM 128
#define BN 128
#define BK 32

template<bool AF32, bool RELU, bool CF32, bool XSWZ>
__global__ __launch_bounds__(256) void gemm_nt(
    const void* __restrict__ Ap, const short* __restrict__ Bp, void* __restrict__ Cp,
    const float* __restrict__ bias, float alpha,
    int K, int lda, int ldb, int ldc,
    long sAz, long sBz, long sCz, long aHX, long sbias)
{
    __shared__ __align__(16) char  AsB[AF32 ? BM * BK * 4 : BM * BK * 2];
    __shared__ __align__(16) short Bs[BN * BK];
    short* AsS = reinterpret_cast<short*>(AsB);
    float* AsF = reinterpret_cast<float*>(AsB);

    int bx, by, bz;
    if constexpr (XSWZ) {
        int id = blockIdx.x + (blockIdx.y << 3) + (blockIdx.z << 8);  // 0..1023
        bx = (id >> 3) & 7;
        int g = (id & 7) | ((id >> 6) << 3);   // A-panel group, same id%8 for all 8 bx
        by = g & 31; bz = g >> 5;
    } else { bx = blockIdx.x; by = blockIdx.y; bz = blockIdx.z; }

    const int t    = threadIdx.x;
    const int m0   = by * BM;
    const int n0   = bx * BN;
    const int z    = bz;
    const int wave = t >> 6, lane = t & 63;
    const int wm   = (wave & 1) * 64, wn = (wave >> 1) * 64;
    const int quad = lane >> 4, l16 = lane & 15;
    const int wofs = t & ~63;                     // wave-uniform slot base

    const short* Bz = Bp + (long)z * sBz;

    // --- staging source pointers (K-loop invariant) ---
    // bf16 tiles: slot = p*256+t; row = slot>>2 (=t>>2 + 64p); col16 = t&3.
    // swizzled col = (t&3) ^ ((row>>1)&3); (row>>1)&3 == (t>>3)&3 for both p.
    const int srow = t >> 2;
    const int ssw  = ((t & 3) ^ ((t >> 3) & 3)) * 8;    // shorts
    const short* bSrc = Bz + (long)(n0 + srow) * ldb + ssw;

    const short* aSrc  = nullptr;
    const float* aSrcF = nullptr;
    if constexpr (AF32) {
        // fp32 A: slot = p*256+t; row = 32p + (t>>3); col16 = t&7.
        // swizzled col = (t&7) ^ (row&7); row&7 == (t>>3)&7 for all p.
        const float* Az = (const float*)Ap + (long)z * sAz;
        aSrcF = Az + (long)(m0 + (t >> 3)) * lda + (((t & 7) ^ ((t >> 3) & 7)) * 4);
    } else {
        const short* Az = (const short*)Ap + (long)z * sAz;
        aSrc = Az + (long)(m0 + srow) * lda + ssw;
    }

    // --- fragment-read constants (i/j-invariant swizzle since 16-row steps) ---
    const int ra = wm + l16, rb = wn + l16;
    const int sa = (quad ^ ((ra >> 1) & 3)) * 8;                 // shorts
    const int sb = (quad ^ ((rb >> 1) & 3)) * 8;                 // shorts
    const int s0 = (((quad << 1)    ) ^ (ra & 7)) * 4;           // floats
    const int s1 = (((quad << 1) | 1) ^ (ra & 7)) * 4;           // floats

    floatx4 acc[4][4] = {};

    for (int k0 = 0; k0 < K; k0 += BK) {
        const long off = (long)k0 + (long)(k0 >> 12) * aHX;
        __syncthreads();                         // prev compute done before overwrite
        if constexpr (AF32) {
            #pragma unroll
            for (int p = 0; p < 4; ++p)
                gload16(aSrcF + (long)p * 32 * lda + off,
                        AsF + (p * 256 + wofs) * 4);
        } else {
            gload16(aSrc + off,                  AsS + wofs * 8);
            gload16(aSrc + (long)64 * lda + off, AsS + (256 + wofs) * 8);
        }
        gload16(bSrc + k0,                  &Bs[wofs * 8]);
        gload16(bSrc + (long)64 * ldb + k0, &Bs[(256 + wofs) * 8]);
        __syncthreads();                         // compiler drains vmcnt(0) here

        shortx8 af[4], bfr[4];
        #pragma unroll
        for (int i = 0; i < 4; ++i) {
            if constexpr (AF32) {
                const float* pf = AsF + (ra + 16 * i) * 32;
                floatx4 f0 = *(const floatx4*)(pf + s0);
                floatx4 f1 = *(const floatx4*)(pf + s1);
                shortx8 s;
                s[0] = f2bf_hw(f0[0]); s[1] = f2bf_hw(f0[1]);
                s[2] = f2bf_hw(f0[2]); s[3] = f2bf_hw(f0[3]);
                s[4] = f2bf_hw(f1[0]); s[5] = f2bf_hw(f1[1]);
                s[6] = f2bf_hw(f1[2]); s[7] = f2bf_hw(f1[3]);
                af[i] = s;
            } else {
                af[i] = *(const shortx8*)(AsS + (ra + 16 * i) * 32 + sa);
            }
        }
        #pragma unroll
        for (int j = 0; j < 4; ++j)
            bfr[j] = *(const shortx8*)(&Bs[(rb + 16 * j) * 32 + sb]);
        #pragma unroll
        for (int i = 0; i < 4; ++i)
            #pragma unroll
            for (int j = 0; j < 4; ++j)
                acc[i][j] = __builtin_amdgcn_mfma_f32_16x16x32_bf16(af[i], bfr[j], acc[i][j], 0, 0, 0);
    }

    // epilogue: C/D layout col=lane&15, row=quad*4+e (m89-verified)
    float bv[4];
    #pragma unroll
    for (int j = 0; j < 4; ++j)
        bv[j] = bias ? (bias + (long)z * sbias)[n0 + wn + j * 16 + l16] : 0.0f;

    #pragma unroll
    for (int i = 0; i < 4; ++i) {
        #pragma unroll
        for (int e = 0; e < 4; ++e) {
            long row = m0 + wm + i * 16 + quad * 4 + e;
            #pragma unroll
            for (int j = 0; j < 4; ++j) {
                float val = acc[i][j][e] * alpha + bv[j];
                if (RELU) val = fmaxf(val, 0.0f);
                long col = n0 + wn + j * 16 + l16;
                if (CF32) ((float*)Cp + (long)z * sCz)[row * ldc + col] = val;
                else      ((short*)Cp + (long)z * sCz)[row * ldc + col] = f2bf(val);
            }
        }
    }
}

// ---------------- softmax(row) * mask, in place on fp32 scores ----------------

__global__ __launch_bounds__(256) void softmax_mask(float* __restrict__ attn,
                                                    const float* __restrict__ mask) {
    float* p = attn + (long)blockIdx.x * 4096;
    const int t = threadIdx.x;
    float v[16];
    float mx = -3.4e38f;
    #pragma unroll
    for (int i = 0; i < 16; ++i) { v[i] = p[t + 256 * i]; mx = fmaxf(mx, v[i]); }
    #pragma unroll
    for (int o = 32; o > 0; o >>= 1) mx = fmaxf(mx, __shfl_down(mx, o));
    __shared__ float r1[4], r2[4];
    const int lane = t & 63, w = t >> 6;
    if (lane == 0) r1[w] = mx;
    __syncthreads();
    mx = fmaxf(fmaxf(r1[0], r1[1]), fmaxf(r1[2], r1[3]));
    float s = 0.f;
    #pragma unroll
    for (int i = 0; i < 16; ++i) { v[i] = __expf(v[i] - mx); s += v[i]; }
    #pragma unroll
    for (int o = 32; o > 0; o >>= 1) s += __shfl_down(s, o);
    if (lane == 0) r2[w] = s;
    __syncthreads();
    s = r2[0] + r2[1] + r2[2] + r2[3];
    const float inv = 1.0f / s;
    #pragma unroll
    for (int i = 0; i < 16; ++i) p[t + 256 * i] = v[i] * inv * mask[t + 256 * i];
}

// ---------------- reduce split-K partials: h = relu(sum_z part_z + b1) -> bf16 ----

__global__ __launch_bounds__(256) void reduce_heads(const short* __restrict__ part,
                                                    const float* __restrict__ b1,
                                                    short* __restrict__ h_bf) {
    int i = blockIdx.x * blockDim.x + threadIdx.x;   // vec8 index over 4M elems
    float s[8] = {0,0,0,0,0,0,0,0};
    #pragma unroll
    for (int z = 0; z < 4; ++z) {
        shortx8 v = ((const shortx8*)(part + (long)z * 4194304))[i];
        #pragma unroll
        for (int e = 0; e < 8; ++e) s[e] += bf2f(v[e]);
    }
    int j0 = (i * 8) & 1023;
    shortx8 o;
    #pragma unroll
    for (int e = 0; e < 8; ++e) o[e] = f2bf(fmaxf(s[e] + b1[j0 + e], 0.f));
    ((shortx8*)h_bf)[i] = o;
}

// ---------------- launch ----------------

extern "C" void kernel_launch(void* const* d_in, const int* in_sizes, int n_in,
                              void* d_out, int out_size, void* d_ws, size_t ws_size,
                              hipStream_t stream) {
    const float* sentences = (const float*)d_in[0];
    const float* knowledge = (const float*)d_in[1];
    const float* mask      = (const float*)d_in[2];
    const float* Ws        = (const float*)d_in[3];
    const float* bs        = (const float*)d_in[4];
    const float* Wk        = (const float*)d_in[5];
    const float* bk        = (const float*)d_in[6];
    const float* W1        = (const float*)d_in[7];
    const float* b1        = (const float*)d_in[8];
    const float* W2        = (const float*)d_in[9];
    const float* b2        = (const float*)d_in[10];

    float* out  = (float*)d_out;
    float* attn = out + 4194304;           // weights region: [8*4096, 4096] fp32

    // ws layout (total ~126 MB):
    //   [0,64M)       V_T      (live: V GEMM -> big GEMM)
    //   [64M,66M)     W2T      (live to end)
    //   [66M,74M)     h_bf     (live: reduce -> final GEMM)
    //   [74M,+16K)    bias2    (bs||bk for batched projection)
    //   pool [77611008, ...):  prep/intermediate buffers, all dead before the
    //                          big GEMM; partials (32 MB bf16) alias pool start.
    char* ws = (char*)d_ws;
    short* V_T     = (short*)(ws);                   // 64 MB  [j][h*4096+m]
    short* W2T     = (short*)(ws + 67108864);        //  2 MB  [j2][j]
    short* h_bf    = (short*)(ws + 69206016);        //  8 MB  [n][j]
    float* bias2   = (float*)(ws + 77594624);        // 16 KB  bs||bk
    short* sent_bf = (short*)(ws + 77611008);        //  8 MB
    short* know_bf = (short*)(ws + 85999616);        //  8 MB
    short* WsT     = (short*)(ws + 94388224);        //  2 MB  [j=h*128+e][d]
    short* WkT     = (short*)(ws + 96485376);        //  2 MB
    short* W1T     = (short*)(ws + 98582528);        // 16 MB  [h][j][d]
    short* S_bf    = (short*)(ws + 115359744);       //  8 MB  [n][h*128+e]
    short* K_bf    = (short*)(ws + 123748352);       //  8 MB  [m][h*128+e]
    short* part    = (short*)(ws + 77611008);        // 32 MB bf16, aliases dead pool
    (void)K_bf;

    // prep: casts + weight transposes + bias pack
    cast_bf16<<<4096, 256, 0, stream>>>(sentences, sent_bf, 1048576);
    cast_bf16<<<4096, 256, 0, stream>>>(knowledge, know_bf, 1048576);
    transpose_cast<<<dim3(4, 32, 8),  dim3(32, 8), 0, stream>>>(Ws, WsT, 1024, 128, 131072, 131072);
    transpose_cast<<<dim3(4, 32, 8),  dim3(32, 8), 0, stream>>>(Wk, WkT, 1024, 128, 131072, 131072);
    transpose_cast<<<dim3(32, 32, 8), dim3(32, 8), 0, stream>>>(W1, W1T, 1024, 1024, 1048576, 1048576);
    transpose_cast<<<dim3(32, 32, 1), dim3(32, 8), 0, stream>>>(W2, W2T, 1024, 1024, 0, 0);
    hipMemcpyAsync(bias2,        bs, 4096, hipMemcpyDeviceToDevice, stream);
    hipMemcpyAsync(bias2 + 1024, bk, 4096, hipMemcpyDeviceToDevice, stream);

    // batched S/K projection: z=0 sentences@Ws+bs, z=1 knowledge@Wk+bk
    gemm_nt<false, false, false, false><<<dim3(8, 32, 2), 256, 0, stream>>>(
        sent_bf, WsT, S_bf, bias2, 1.0f, 1024, 1024, 1024, 1024,
        4194304, 1048576, 4194304, 0, 1024);
    // V_T[j][h*4096+m] = (knowledge @ W1_h)[m][j]
    gemm_nt<false, false, false, false><<<dim3(32, 8, 8), 256, 0, stream>>>(
        W1T, know_bf, V_T, nullptr, 1.0f, 1024, 1024, 1024, 32768,
        1048576, 0, 4096, 0, 0);
    // raw scores -> d_out weights region (fp32), scaled 1/sqrt(128)
    gemm_nt<false, false, true, false><<<dim3(32, 32, 8), 256, 0, stream>>>(
        S_bf, K_bf, attn, nullptr, 0.08838834764831845f, 128, 1024, 1024, 4096,
        128, 128, 16777216, 0, 0);
    // softmax over knowledge dim + post-softmax mask, in place
    softmax_mask<<<32768, 256, 0, stream>>>(attn, mask);
    // big GEMM, split-K over head pairs: part[z] = attn[:, z-pair] @ V_T[z-pair]^T
    // z in [0,4): heads 2z,2z+1; K=8192; A fp32 from d_out; XCD-swizzled grid
    gemm_nt<true, false, false, true><<<dim3(8, 32, 4), 256, 0, stream>>>(
        attn, V_T, part, nullptr, 1.0f, 8192, 4096, 32768, 1024,
        33554432, 8192, 4194304, 16777216 - 4096, 0);
    // h = relu(sum_z part_z + b1) -> bf16
    reduce_heads<<<2048, 256, 0, stream>>>(part, b1, h_bf);
    // output = h @ W2 + b2 -> d_out[0:4M] fp32
    gemm_nt<false, false, true, false><<<dim3(8, 32, 1), 256, 0, stream>>>(
        h_bf, W2T, out, b2, 1.0f, 1024, 1024, 1024, 1024, 0, 0, 0, 0, 0);
}

// Round 2
// 1547.828 us; speedup vs baseline: 1.1002x; 1.0372x over previous
//
#include <hip/hip_runtime.h>
#include <hip/hip_bf16.h>

typedef __attribute__((ext_vector_type(4))) float  floatx4;
typedef __attribute__((ext_vector_type(8))) short  shortx8;
typedef __attribute__((ext_vector_type(4))) short  shortx4;

__device__ __forceinline__ short f2bf(float x) {
    union { float f; unsigned u; } v; v.f = x;
    unsigned r = v.u + 0x7FFFu + ((v.u >> 16) & 1u);   // round-to-nearest-even
    return (short)(r >> 16);
}
__device__ __forceinline__ float bf2f(short x) {
    union { unsigned u; float f; } c; c.u = ((unsigned)(unsigned short)x) << 16;
    return c.f;
}
// hardware RNE f32->bf16 (compiler emits v_cvt_pk_bf16_f32; same rounding as f2bf)
__device__ __forceinline__ short f2bf_hw(float x) {
    union { __hip_bfloat16 h; short s; } u;
    u.h = __float2bfloat16(x);
    return u.s;
}

// async global->LDS, 16 B per lane; LDS dest must be wave-uniform base + lane*16
__device__ __forceinline__ void gload16(const void* g, void* l) {
    __builtin_amdgcn_global_load_lds(
        (const __attribute__((address_space(1))) void*)g,
        (__attribute__((address_space(3))) void*)l, 16, 0, 0);
}

// ---------------- prep kernels ----------------

__global__ void cast_bf16(const float* __restrict__ src, short* __restrict__ dst, int n4) {
    int i = blockIdx.x * blockDim.x + threadIdx.x;
    if (i < n4) {
        floatx4 v = ((const floatx4*)src)[i];
        shortx4 s;
        s[0] = f2bf(v[0]); s[1] = f2bf(v[1]); s[2] = f2bf(v[2]); s[3] = f2bf(v[3]);
        ((shortx4*)dst)[i] = s;
    }
}

// dst[c][r] = (bf16)src[r][c], per-z batch. src: R x C fp32. dst: C x R bf16.
__global__ void transpose_cast(const float* __restrict__ src, short* __restrict__ dst,
                               int R, int C, long szSrc, long szDst) {
    __shared__ float tile[32][33];
    const float* s = src + (long)blockIdx.z * szSrc;
    short* d = dst + (long)blockIdx.z * szDst;
    int c0 = blockIdx.x * 32, r0 = blockIdx.y * 32;
    for (int i = threadIdx.y; i < 32; i += 8)
        tile[i][threadIdx.x] = s[(long)(r0 + i) * C + c0 + threadIdx.x];
    __syncthreads();
    for (int i = threadIdx.y; i < 32; i += 8)
        d[(long)(c0 + i) * R + r0 + threadIdx.x] = f2bf(tile[threadIdx.x][i]);
}

// ---------------- NT GEMM: C[M,N] = A[M,K] * B[N,K]^T ----------------
// 2-phase double-buffered pipeline (T3-minimum + T4, guide §5.5):
// per iter: ds_read frags from buf[cur]  ->  issue global_load_lds for t+1
// into buf[cur^1]  ->  MFMA  ->  __syncthreads() (vmcnt(0) drain lands AFTER
// a full MFMA phase of latency hiding). One barrier per K-step.
// Staging via global_load_lds width=16; LDS LINEAR; bank-conflict avoidance by
// XOR-swizzling the *global source column* and applying the same involution on
// the read side (rule #21):
//   bf16 tiles (64 B rows, 4x 16B slots):  slot ^= (row>>1)&3
//   fp32 A tile (128 B rows, 8x 16B slots): slot ^= row&7
// AF32: A stays fp32 in LDS; converted to bf16 at fragment read (hw cvt, RNE).
// XSWZ (grid must be (8,32,4)): bijective remap so the 8 n-blocks sharing one
// A-panel land on one XCD (XCD = dispatch_index % 8) -> A-panel hits L2 once.
// aHX: extra element offset added per 4096 of block-local k (per-head layout).

#define BM 128
#define BN 128
#define BK 32

template<bool AF32, bool RELU, bool CF32, bool XSWZ>
__global__ __launch_bounds__(256) void gemm_nt(
    const void* __restrict__ Ap, const short* __restrict__ Bp, void* __restrict__ Cp,
    const float* __restrict__ bias, float alpha,
    int K, int lda, int ldb, int ldc,
    long sAz, long sBz, long sCz, long aHX, long sbias)
{
    constexpr int ABYTES = AF32 ? (BM * BK * 4) : (BM * BK * 2);
    __shared__ __align__(16) char  AsB[2 * ABYTES];
    __shared__ __align__(16) short Bs[2 * BN * BK];

    int bx, by, bz;
    if constexpr (XSWZ) {
        int id = blockIdx.x + (blockIdx.y << 3) + (blockIdx.z << 8);  // 0..1023
        bx = (id >> 3) & 7;
        int g = (id & 7) | ((id >> 6) << 3);   // A-panel group, same id%8 for all 8 bx
        by = g & 31; bz = g >> 5;
    } else { bx = blockIdx.x; by = blockIdx.y; bz = blockIdx.z; }

    const int t    = threadIdx.x;
    const int m0   = by * BM;
    const int n0   = bx * BN;
    const int z    = bz;
    const int wave = t >> 6, lane = t & 63;
    const int wm   = (wave & 1) * 64, wn = (wave >> 1) * 64;
    const int quad = lane >> 4, l16 = lane & 15;
    const int wofs = t & ~63;                     // wave-uniform slot base

    const short* Bz = Bp + (long)z * sBz;

    // --- staging source pointers (K-loop invariant) ---
    // bf16 tiles: slot = p*256+t; row = slot>>2 (=t>>2 + 64p); col16 = t&3.
    // swizzled col = (t&3) ^ ((row>>1)&3); (row>>1)&3 == (t>>3)&3 for both p.
    const int srow = t >> 2;
    const int ssw  = ((t & 3) ^ ((t >> 3) & 3)) * 8;    // shorts
    const short* bSrc = Bz + (long)(n0 + srow) * ldb + ssw;

    const short* aSrc  = nullptr;
    const float* aSrcF = nullptr;
    if constexpr (AF32) {
        // fp32 A: slot = p*256+t; row = 32p + (t>>3); col16 = t&7.
        // swizzled col = (t&7) ^ (row&7); row&7 == (t>>3)&7 for all p.
        const float* Az = (const float*)Ap + (long)z * sAz;
        aSrcF = Az + (long)(m0 + (t >> 3)) * lda + (((t & 7) ^ ((t >> 3) & 7)) * 4);
    } else {
        const short* Az = (const short*)Ap + (long)z * sAz;
        aSrc = Az + (long)(m0 + srow) * lda + ssw;
    }

    // --- fragment-read constants (i/j-invariant swizzle since 16-row steps) ---
    const int ra = wm + l16, rb = wn + l16;
    const int sa = (quad ^ ((ra >> 1) & 3)) * 8;                 // shorts
    const int sb = (quad ^ ((rb >> 1) & 3)) * 8;                 // shorts
    const int s0 = (((quad << 1)    ) ^ (ra & 7)) * 4;           // floats
    const int s1 = (((quad << 1) | 1) ^ (ra & 7)) * 4;           // floats

    auto stage = [&](int buf, int kk) {
        const long off = (long)kk + (long)(kk >> 12) * aHX;
        if constexpr (AF32) {
            float* ad = (float*)(AsB + buf * ABYTES);
            #pragma unroll
            for (int p = 0; p < 4; ++p)
                gload16(aSrcF + (long)p * 32 * lda + off, ad + (p * 256 + wofs) * 4);
        } else {
            short* ad = (short*)(AsB + buf * ABYTES);
            gload16(aSrc + off,                 ad + wofs * 8);
            gload16(aSrc + (long)64 * lda + off, ad + (256 + wofs) * 8);
        }
        short* bd = Bs + buf * (BN * BK);
        gload16(bSrc + kk,                  bd + wofs * 8);
        gload16(bSrc + (long)64 * ldb + kk, bd + (256 + wofs) * 8);
    };

    floatx4 acc[4][4] = {};

    stage(0, 0);
    __syncthreads();                 // drains prologue vmcnt

    const int nt = K / BK;
    for (int tt = 0; tt < nt; ++tt) {
        const int cur = tt & 1;
        const short* AsS = (const short*)(AsB + cur * ABYTES);
        const float* AsF = (const float*)(AsB + cur * ABYTES);
        const short* BsC = Bs + cur * (BN * BK);

        // 1) fragment ds_reads from current buffer (issued first)
        shortx8 af[4], bfr[4];
        floatx4 fa[4][2];
        #pragma unroll
        for (int i = 0; i < 4; ++i) {
            if constexpr (AF32) {
                const float* pf = AsF + (ra + 16 * i) * 32;
                fa[i][0] = *(const floatx4*)(pf + s0);
                fa[i][1] = *(const floatx4*)(pf + s1);
            } else {
                af[i] = *(const shortx8*)(AsS + (ra + 16 * i) * 32 + sa);
            }
        }
        #pragma unroll
        for (int j = 0; j < 4; ++j)
            bfr[j] = *(const shortx8*)(BsC + (rb + 16 * j) * 32 + sb);

        // 2) issue next tile's async loads into the other buffer
        if (tt + 1 < nt) stage(cur ^ 1, (tt + 1) * BK);

        // 3) convert (AF32) + MFMA; loads stay in flight underneath
        if constexpr (AF32) {
            #pragma unroll
            for (int i = 0; i < 4; ++i) {
                shortx8 s;
                s[0] = f2bf_hw(fa[i][0][0]); s[1] = f2bf_hw(fa[i][0][1]);
                s[2] = f2bf_hw(fa[i][0][2]); s[3] = f2bf_hw(fa[i][0][3]);
                s[4] = f2bf_hw(fa[i][1][0]); s[5] = f2bf_hw(fa[i][1][1]);
                s[6] = f2bf_hw(fa[i][1][2]); s[7] = f2bf_hw(fa[i][1][3]);
                af[i] = s;
            }
        }
        #pragma unroll
        for (int i = 0; i < 4; ++i)
            #pragma unroll
            for (int j = 0; j < 4; ++j)
                acc[i][j] = __builtin_amdgcn_mfma_f32_16x16x32_bf16(af[i], bfr[j], acc[i][j], 0, 0, 0);

        // 4) single drain+barrier per K-step; next-tile loads had the whole
        //    MFMA phase to complete
        __syncthreads();
    }

    // epilogue: C/D layout col=lane&15, row=quad*4+e (m89-verified)
    float bv[4];
    #pragma unroll
    for (int j = 0; j < 4; ++j)
        bv[j] = bias ? (bias + (long)z * sbias)[n0 + wn + j * 16 + l16] : 0.0f;

    #pragma unroll
    for (int i = 0; i < 4; ++i) {
        #pragma unroll
        for (int e = 0; e < 4; ++e) {
            long row = m0 + wm + i * 16 + quad * 4 + e;
            #pragma unroll
            for (int j = 0; j < 4; ++j) {
                float val = acc[i][j][e] * alpha + bv[j];
                if (RELU) val = fmaxf(val, 0.0f);
                long col = n0 + wn + j * 16 + l16;
                if (CF32) ((float*)Cp + (long)z * sCz)[row * ldc + col] = val;
                else      ((short*)Cp + (long)z * sCz)[row * ldc + col] = f2bf(val);
            }
        }
    }
}

// ---------------- softmax(row) * mask, in place on fp32 scores ----------------
// vectorized floatx4 (G13): one row (16 KB) per block, 256 threads x 4 vec4.

__global__ __launch_bounds__(256) void softmax_mask(float* __restrict__ attn,
                                                    const float* __restrict__ mask) {
    float* p = attn + (long)blockIdx.x * 4096;
    const int t = threadIdx.x;
    floatx4 v[4];
    float mx = -3.4e38f;
    #pragma unroll
    for (int i = 0; i < 4; ++i) {
        v[i] = ((const floatx4*)p)[t + 256 * i];
        mx = fmaxf(mx, fmaxf(fmaxf(v[i][0], v[i][1]), fmaxf(v[i][2], v[i][3])));
    }
    #pragma unroll
    for (int o = 32; o > 0; o >>= 1) mx = fmaxf(mx, __shfl_down(mx, o));
    __shared__ float r1[4], r2[4];
    const int lane = t & 63, w = t >> 6;
    if (lane == 0) r1[w] = mx;
    __syncthreads();
    mx = fmaxf(fmaxf(r1[0], r1[1]), fmaxf(r1[2], r1[3]));
    float s = 0.f;
    #pragma unroll
    for (int i = 0; i < 4; ++i) {
        #pragma unroll
        for (int e = 0; e < 4; ++e) { v[i][e] = __expf(v[i][e] - mx); s += v[i][e]; }
    }
    #pragma unroll
    for (int o = 32; o > 0; o >>= 1) s += __shfl_down(s, o);
    if (lane == 0) r2[w] = s;
    __syncthreads();
    s = r2[0] + r2[1] + r2[2] + r2[3];
    const float inv = 1.0f / s;
    #pragma unroll
    for (int i = 0; i < 4; ++i) {
        floatx4 mv = ((const floatx4*)mask)[t + 256 * i];
        floatx4 o;
        #pragma unroll
        for (int e = 0; e < 4; ++e) o[e] = v[i][e] * inv * mv[e];
        ((floatx4*)p)[t + 256 * i] = o;
    }
}

// ---------------- reduce split-K partials: h = relu(sum_z part_z + b1) -> bf16 ----

__global__ __launch_bounds__(256) void reduce_heads(const short* __restrict__ part,
                                                    const float* __restrict__ b1,
                                                    short* __restrict__ h_bf) {
    int i = blockIdx.x * blockDim.x + threadIdx.x;   // vec8 index over 4M elems
    float s[8] = {0,0,0,0,0,0,0,0};
    #pragma unroll
    for (int z = 0; z < 4; ++z) {
        shortx8 v = ((const shortx8*)(part + (long)z * 4194304))[i];
        #pragma unroll
        for (int e = 0; e < 8; ++e) s[e] += bf2f(v[e]);
    }
    int j0 = (i * 8) & 1023;
    shortx8 o;
    #pragma unroll
    for (int e = 0; e < 8; ++e) o[e] = f2bf(fmaxf(s[e] + b1[j0 + e], 0.f));
    ((shortx8*)h_bf)[i] = o;
}

// ---------------- launch ----------------

extern "C" void kernel_launch(void* const* d_in, const int* in_sizes, int n_in,
                              void* d_out, int out_size, void* d_ws, size_t ws_size,
                              hipStream_t stream) {
    const float* sentences = (const float*)d_in[0];
    const float* knowledge = (const float*)d_in[1];
    const float* mask      = (const float*)d_in[2];
    const float* Ws        = (const float*)d_in[3];
    const float* bs        = (const float*)d_in[4];
    const float* Wk        = (const float*)d_in[5];
    const float* bk        = (const float*)d_in[6];
    const float* W1        = (const float*)d_in[7];
    const float* b1        = (const float*)d_in[8];
    const float* W2        = (const float*)d_in[9];
    const float* b2        = (const float*)d_in[10];

    float* out  = (float*)d_out;
    float* attn = out + 4194304;           // weights region: [8*4096, 4096] fp32

    // ws layout (total ~126 MB):
    //   [0,64M)       V_T      (live: V GEMM -> big GEMM)
    //   [64M,66M)     W2T      (live to end)
    //   [66M,74M)     h_bf     (live: reduce -> final GEMM)
    //   [74M,+16K)    bias2    (bs||bk for batched projection)
    //   pool [77611008, ...):  prep/intermediate buffers, all dead before the
    //                          big GEMM; partials (32 MB bf16) alias pool start.
    char* ws = (char*)d_ws;
    short* V_T     = (short*)(ws);                   // 64 MB  [j][h*4096+m]
    short* W2T     = (short*)(ws + 67108864);        //  2 MB  [j2][j]
    short* h_bf    = (short*)(ws + 69206016);        //  8 MB  [n][j]
    float* bias2   = (float*)(ws + 77594624);        // 16 KB  bs||bk
    short* sent_bf = (short*)(ws + 77611008);        //  8 MB
    short* know_bf = (short*)(ws + 85999616);        //  8 MB
    short* WsT     = (short*)(ws + 94388224);        //  2 MB  [j=h*128+e][d]
    short* WkT     = (short*)(ws + 96485376);        //  2 MB
    short* W1T     = (short*)(ws + 98582528);        // 16 MB  [h][j][d]
    short* S_bf    = (short*)(ws + 115359744);       //  8 MB  [n][h*128+e]
    short* K_bf    = (short*)(ws + 123748352);       //  8 MB  [m][h*128+e]
    short* part    = (short*)(ws + 77611008);        // 32 MB bf16, aliases dead pool
    (void)K_bf;

    // prep: casts + weight transposes + bias pack
    cast_bf16<<<4096, 256, 0, stream>>>(sentences, sent_bf, 1048576);
    cast_bf16<<<4096, 256, 0, stream>>>(knowledge, know_bf, 1048576);
    transpose_cast<<<dim3(4, 32, 8),  dim3(32, 8), 0, stream>>>(Ws, WsT, 1024, 128, 131072, 131072);
    transpose_cast<<<dim3(4, 32, 8),  dim3(32, 8), 0, stream>>>(Wk, WkT, 1024, 128, 131072, 131072);
    transpose_cast<<<dim3(32, 32, 8), dim3(32, 8), 0, stream>>>(W1, W1T, 1024, 1024, 1048576, 1048576);
    transpose_cast<<<dim3(32, 32, 1), dim3(32, 8), 0, stream>>>(W2, W2T, 1024, 1024, 0, 0);
    hipMemcpyAsync(bias2,        bs, 4096, hipMemcpyDeviceToDevice, stream);
    hipMemcpyAsync(bias2 + 1024, bk, 4096, hipMemcpyDeviceToDevice, stream);

    // batched S/K projection: z=0 sentences@Ws+bs, z=1 knowledge@Wk+bk
    gemm_nt<false, false, false, false><<<dim3(8, 32, 2), 256, 0, stream>>>(
        sent_bf, WsT, S_bf, bias2, 1.0f, 1024, 1024, 1024, 1024,
        4194304, 1048576, 4194304, 0, 1024);
    // V_T[j][h*4096+m] = (knowledge @ W1_h)[m][j]
    gemm_nt<false, false, false, false><<<dim3(32, 8, 8), 256, 0, stream>>>(
        W1T, know_bf, V_T, nullptr, 1.0f, 1024, 1024, 1024, 32768,
        1048576, 0, 4096, 0, 0);
    // raw scores -> d_out weights region (fp32), scaled 1/sqrt(128)
    gemm_nt<false, false, true, false><<<dim3(32, 32, 8), 256, 0, stream>>>(
        S_bf, K_bf, attn, nullptr, 0.08838834764831845f, 128, 1024, 1024, 4096,
        128, 128, 16777216, 0, 0);
    // softmax over knowledge dim + post-softmax mask, in place
    softmax_mask<<<32768, 256, 0, stream>>>(attn, mask);
    // big GEMM, split-K over head pairs: part[z] = attn[:, z-pair] @ V_T[z-pair]^T
    // z in [0,4): heads 2z,2z+1; K=8192; A fp32 from d_out; XCD-swizzled grid
    gemm_nt<true, false, false, true><<<dim3(8, 32, 4), 256, 0, stream>>>(
        attn, V_T, part, nullptr, 1.0f, 8192, 4096, 32768, 1024,
        33554432, 8192, 4194304, 16777216 - 4096, 0);
    // h = relu(sum_z part_z + b1) -> bf16
    reduce_heads<<<2048, 256, 0, stream>>>(part, b1, h_bf);
    // output = h @ W2 + b2 -> d_out[0:4M] fp32
    gemm_nt<false, false, true, false><<<dim3(8, 32, 1), 256, 0, stream>>>(
        h_bf, W2T, out, b2, 1.0f, 1024, 1024, 1024, 1024, 0, 0, 0, 0, 0);
}

// Round 3
// 1546.605 us; speedup vs baseline: 1.1010x; 1.0008x over previous
//
#include <hip/hip_runtime.h>
#include <hip/hip_bf16.h>

typedef __attribute__((ext_vector_type(4))) float  floatx4;
typedef __attribute__((ext_vector_type(8))) short  shortx8;
typedef __attribute__((ext_vector_type(4))) short  shortx4;

__device__ __forceinline__ short f2bf(float x) {
    union { float f; unsigned u; } v; v.f = x;
    unsigned r = v.u + 0x7FFFu + ((v.u >> 16) & 1u);   // round-to-nearest-even
    return (short)(r >> 16);
}
__device__ __forceinline__ float bf2f(short x) {
    union { unsigned u; float f; } c; c.u = ((unsigned)(unsigned short)x) << 16;
    return c.f;
}
// hardware RNE f32->bf16 (compiler emits v_cvt_pk_bf16_f32; same rounding as f2bf)
__device__ __forceinline__ short f2bf_hw(float x) {
    union { __hip_bfloat16 h; short s; } u;
    u.h = __float2bfloat16(x);
    return u.s;
}

// async global->LDS, 16 B per lane; LDS dest must be wave-uniform base + lane*16
__device__ __forceinline__ void gload16(const void* g, void* l) {
    __builtin_amdgcn_global_load_lds(
        (const __attribute__((address_space(1))) void*)g,
        (__attribute__((address_space(3))) void*)l, 16, 0, 0);
}

// ---------------- prep kernels ----------------

__global__ void cast_bf16(const float* __restrict__ src, short* __restrict__ dst, int n4) {
    int i = blockIdx.x * blockDim.x + threadIdx.x;
    if (i < n4) {
        floatx4 v = ((const floatx4*)src)[i];
        shortx4 s;
        s[0] = f2bf(v[0]); s[1] = f2bf(v[1]); s[2] = f2bf(v[2]); s[3] = f2bf(v[3]);
        ((shortx4*)dst)[i] = s;
    }
}

// dst[c][r] = (bf16)src[r][c], per-z batch. src: R x C fp32. dst: C x R bf16.
__global__ void transpose_cast(const float* __restrict__ src, short* __restrict__ dst,
                               int R, int C, long szSrc, long szDst) {
    __shared__ float tile[32][33];
    const float* s = src + (long)blockIdx.z * szSrc;
    short* d = dst + (long)blockIdx.z * szDst;
    int c0 = blockIdx.x * 32, r0 = blockIdx.y * 32;
    for (int i = threadIdx.y; i < 32; i += 8)
        tile[i][threadIdx.x] = s[(long)(r0 + i) * C + c0 + threadIdx.x];
    __syncthreads();
    for (int i = threadIdx.y; i < 32; i += 8)
        d[(long)(c0 + i) * R + r0 + threadIdx.x] = f2bf(tile[threadIdx.x][i]);
}

// ---------------- NT GEMM: C[M,N] = A[M,K] * B[N,K]^T (bf16 A and B) --------
// 2-phase double-buffered: ds_read frags buf[cur] -> issue t+1 gloads into
// buf[cur^1] -> MFMA -> __syncthreads (vmcnt(0) drain lands after the MFMA
// phase). Staging via global_load_lds width=16; LDS LINEAR; bank-conflict
// avoidance by XOR-swizzling the *global source column* and applying the same
// involution on the read side (rule #21): slot ^= (row>>1)&3  (64 B rows).

#define BM 128
#define BN 128
#define BK 32

template<bool RELU, bool CF32>
__global__ __launch_bounds__(256) void gemm_nt(
    const short* __restrict__ Ap, const short* __restrict__ Bp, void* __restrict__ Cp,
    const float* __restrict__ bias, float alpha,
    int K, int lda, int ldb, int ldc,
    long sAz, long sBz, long sCz, long sbias)
{
    __shared__ __align__(16) short As[2][BM * BK];
    __shared__ __align__(16) short Bs[2][BN * BK];

    const int bx = blockIdx.x, by = blockIdx.y, bz = blockIdx.z;
    const int t    = threadIdx.x;
    const int m0   = by * BM;
    const int n0   = bx * BN;
    const int wave = t >> 6, lane = t & 63;
    const int wm   = (wave & 1) * 64, wn = (wave >> 1) * 64;
    const int quad = lane >> 4, l16 = lane & 15;
    const int wofs = t & ~63;                     // wave-uniform slot base

    // staging: slot = p*256+t; row = t>>2 + 64p; col16 = t&3.
    // swizzled col = (t&3) ^ ((row>>1)&3); (row>>1)&3 == (t>>3)&3 for both p.
    const int srow = t >> 2;
    const int ssw  = ((t & 3) ^ ((t >> 3) & 3)) * 8;    // shorts
    const short* aSrc = Ap + (long)bz * sAz + (long)(m0 + srow) * lda + ssw;
    const short* bSrc = Bp + (long)bz * sBz + (long)(n0 + srow) * ldb + ssw;

    // fragment-read constants (i/j-invariant: 16-row steps keep (row>>1)&3)
    const int ra = wm + l16, rb = wn + l16;
    const int sa = (quad ^ ((ra >> 1) & 3)) * 8;
    const int sb = (quad ^ ((rb >> 1) & 3)) * 8;

    auto stage = [&](int buf, int kk) {
        gload16(aSrc + kk,                  &As[buf][wofs * 8]);
        gload16(aSrc + (long)64 * lda + kk, &As[buf][(256 + wofs) * 8]);
        gload16(bSrc + kk,                  &Bs[buf][wofs * 8]);
        gload16(bSrc + (long)64 * ldb + kk, &Bs[buf][(256 + wofs) * 8]);
    };

    floatx4 acc[4][4] = {};

    stage(0, 0);
    __syncthreads();                 // drains prologue vmcnt

    const int nt = K / BK;
    for (int tt = 0; tt < nt; ++tt) {
        const int cur = tt & 1;

        shortx8 af[4], bfr[4];
        #pragma unroll
        for (int i = 0; i < 4; ++i)
            af[i] = *(const shortx8*)(&As[cur][(ra + 16 * i) * 32 + sa]);
        #pragma unroll
        for (int j = 0; j < 4; ++j)
            bfr[j] = *(const shortx8*)(&Bs[cur][(rb + 16 * j) * 32 + sb]);

        if (tt + 1 < nt) stage(cur ^ 1, (tt + 1) * BK);

        #pragma unroll
        for (int i = 0; i < 4; ++i)
            #pragma unroll
            for (int j = 0; j < 4; ++j)
                acc[i][j] = __builtin_amdgcn_mfma_f32_16x16x32_bf16(af[i], bfr[j], acc[i][j], 0, 0, 0);

        __syncthreads();
    }

    // epilogue: C/D layout col=lane&15, row=quad*4+e (m89-verified)
    float bv[4];
    #pragma unroll
    for (int j = 0; j < 4; ++j)
        bv[j] = bias ? (bias + (long)bz * sbias)[n0 + wn + j * 16 + l16] : 0.0f;

    #pragma unroll
    for (int i = 0; i < 4; ++i) {
        #pragma unroll
        for (int e = 0; e < 4; ++e) {
            long row = m0 + wm + i * 16 + quad * 4 + e;
            #pragma unroll
            for (int j = 0; j < 4; ++j) {
                float val = acc[i][j][e] * alpha + bv[j];
                if (RELU) val = fmaxf(val, 0.0f);
                long col = n0 + wn + j * 16 + l16;
                if (CF32) ((float*)Cp + (long)bz * sCz)[row * ldc + col] = val;
                else      ((short*)Cp + (long)bz * sCz)[row * ldc + col] = f2bf(val);
            }
        }
    }
}

// ---------------- attn@V GEMM: A fp32 (reg-staged -> bf16 LDS), B bf16 -------
// T14 split: A global loads + B global_load_lds for t+1 issued at TOP of iter
// t (full-iter latency cover); cvt+ds_write of A after the MFMA block (the
// compiler's vmcnt wait for the A regs lands there). LDS 32 KB -> 4-5
// blocks/CU. Same XOR swizzle as gemm_nt, applied at ds_write (A) / source
// (B) and on the fragment reads.
// Grid MUST be (8,32,4); XCD-bijective swizzle groups the 8 n-blocks of one
// A-panel onto one XCD. aHX: extra elem offset per 4096 of k (head stride).

__global__ __launch_bounds__(256, 4) void gemm_attnv(
    const float* __restrict__ Ap, const short* __restrict__ Bp, short* __restrict__ Cp,
    int K, int lda, int ldb, int ldc,
    long sAz, long sBz, long sCz, long aHX)
{
    __shared__ __align__(16) short As[2][BM * BK];
    __shared__ __align__(16) short Bs[2][BN * BK];

    int id = blockIdx.x + (blockIdx.y << 3) + (blockIdx.z << 8);  // 0..1023
    int bx = (id >> 3) & 7;
    int g  = (id & 7) | ((id >> 6) << 3);   // same id%8 for all 8 bx of a panel
    int by = g & 31, bz = g >> 5;

    const int t    = threadIdx.x;
    const int m0   = by * BM, n0 = bx * BN;
    const int wave = t >> 6, lane = t & 63;
    const int wm   = (wave & 1) * 64, wn = (wave >> 1) * 64;
    const int quad = lane >> 4, l16 = lane & 15;
    const int wofs = t & ~63;

    // B staging via global_load_lds (source-swizzled)
    const int srow = t >> 2;
    const int ssw  = ((t & 3) ^ ((t >> 3) & 3)) * 8;
    const short* bSrc = Bp + (long)bz * sBz + (long)(n0 + srow) * ldb + ssw;

    // A reg-staging: thread owns row arow = t>>1, k-half akh = t&1 (16 k)
    const int arow = t >> 1, akh = t & 1;
    const int afr  = (arow >> 1) & 3;                  // row XOR key
    const float* aSrc = Ap + (long)bz * sAz + (long)(m0 + arow) * lda + 16 * akh;
    const int aw0 = arow * 32 + (((akh << 1)    ) ^ afr) * 8;   // shorts
    const int aw1 = arow * 32 + (((akh << 1) | 1) ^ afr) * 8;

    const int ra = wm + l16, rb = wn + l16;
    const int sa = (quad ^ ((ra >> 1) & 3)) * 8;
    const int sb = (quad ^ ((rb >> 1) & 3)) * 8;

    floatx4 acc[4][4] = {};
    const int nt = K / BK;
    floatx4 fA[4];

    auto aload = [&](int kk) {
        const long off = (long)kk + (long)(kk >> 12) * aHX;
        const float* p = aSrc + off;
        fA[0] = *(const floatx4*)(p);
        fA[1] = *(const floatx4*)(p + 4);
        fA[2] = *(const floatx4*)(p + 8);
        fA[3] = *(const floatx4*)(p + 12);
    };
    auto awrite = [&](int buf) {
        shortx8 w0, w1;
        w0[0]=f2bf_hw(fA[0][0]); w0[1]=f2bf_hw(fA[0][1]); w0[2]=f2bf_hw(fA[0][2]); w0[3]=f2bf_hw(fA[0][3]);
        w0[4]=f2bf_hw(fA[1][0]); w0[5]=f2bf_hw(fA[1][1]); w0[6]=f2bf_hw(fA[1][2]); w0[7]=f2bf_hw(fA[1][3]);
        w1[0]=f2bf_hw(fA[2][0]); w1[1]=f2bf_hw(fA[2][1]); w1[2]=f2bf_hw(fA[2][2]); w1[3]=f2bf_hw(fA[2][3]);
        w1[4]=f2bf_hw(fA[3][0]); w1[5]=f2bf_hw(fA[3][1]); w1[6]=f2bf_hw(fA[3][2]); w1[7]=f2bf_hw(fA[3][3]);
        *(shortx8*)(&As[buf][aw0]) = w0;
        *(shortx8*)(&As[buf][aw1]) = w1;
    };
    auto bstage = [&](int buf, int kk) {
        gload16(bSrc + kk,                  &Bs[buf][wofs * 8]);
        gload16(bSrc + (long)64 * ldb + kk, &Bs[buf][(256 + wofs) * 8]);
    };

    // prologue: tile 0
    aload(0);
    bstage(0, 0);
    awrite(0);
    __syncthreads();

    for (int tt = 0; tt < nt; ++tt) {
        const int cur = tt & 1;

        // issue next tile's global loads first (oldest in flight, full cover)
        if (tt + 1 < nt) {
            aload((tt + 1) * BK);
            bstage(cur ^ 1, (tt + 1) * BK);
        }

        shortx8 af[4], bfr[4];
        #pragma unroll
        for (int i = 0; i < 4; ++i)
            af[i] = *(const shortx8*)(&As[cur][(ra + 16 * i) * 32 + sa]);
        #pragma unroll
        for (int j = 0; j < 4; ++j)
            bfr[j] = *(const shortx8*)(&Bs[cur][(rb + 16 * j) * 32 + sb]);

        #pragma unroll
        for (int i = 0; i < 4; ++i)
            #pragma unroll
            for (int j = 0; j < 4; ++j)
                acc[i][j] = __builtin_amdgcn_mfma_f32_16x16x32_bf16(af[i], bfr[j], acc[i][j], 0, 0, 0);

        // convert + LDS-write next A (A-reg vmcnt wait lands here, post-MFMA)
        if (tt + 1 < nt) awrite(cur ^ 1);

        __syncthreads();
    }

    // epilogue: C bf16, no bias/alpha
    #pragma unroll
    for (int i = 0; i < 4; ++i) {
        #pragma unroll
        for (int e = 0; e < 4; ++e) {
            long row = m0 + wm + i * 16 + quad * 4 + e;
            #pragma unroll
            for (int j = 0; j < 4; ++j) {
                long col = n0 + wn + j * 16 + l16;
                (Cp + (long)bz * sCz)[row * ldc + col] = f2bf(acc[i][j][e]);
            }
        }
    }
}

// ---------------- softmax(row) * mask, in place on fp32 scores ----------------
// vectorized floatx4 (G13): one row (16 KB) per block, 256 threads x 4 vec4.

__global__ __launch_bounds__(256) void softmax_mask(float* __restrict__ attn,
                                                    const float* __restrict__ mask) {
    float* p = attn + (long)blockIdx.x * 4096;
    const int t = threadIdx.x;
    floatx4 v[4];
    float mx = -3.4e38f;
    #pragma unroll
    for (int i = 0; i < 4; ++i) {
        v[i] = ((const floatx4*)p)[t + 256 * i];
        mx = fmaxf(mx, fmaxf(fmaxf(v[i][0], v[i][1]), fmaxf(v[i][2], v[i][3])));
    }
    #pragma unroll
    for (int o = 32; o > 0; o >>= 1) mx = fmaxf(mx, __shfl_down(mx, o));
    __shared__ float r1[4], r2[4];
    const int lane = t & 63, w = t >> 6;
    if (lane == 0) r1[w] = mx;
    __syncthreads();
    mx = fmaxf(fmaxf(r1[0], r1[1]), fmaxf(r1[2], r1[3]));
    float s = 0.f;
    #pragma unroll
    for (int i = 0; i < 4; ++i) {
        #pragma unroll
        for (int e = 0; e < 4; ++e) { v[i][e] = __expf(v[i][e] - mx); s += v[i][e]; }
    }
    #pragma unroll
    for (int o = 32; o > 0; o >>= 1) s += __shfl_down(s, o);
    if (lane == 0) r2[w] = s;
    __syncthreads();
    s = r2[0] + r2[1] + r2[2] + r2[3];
    const float inv = 1.0f / s;
    #pragma unroll
    for (int i = 0; i < 4; ++i) {
        floatx4 mv = ((const floatx4*)mask)[t + 256 * i];
        floatx4 o;
        #pragma unroll
        for (int e = 0; e < 4; ++e) o[e] = v[i][e] * inv * mv[e];
        ((floatx4*)p)[t + 256 * i] = o;
    }
}

// ---------------- reduce split-K partials: h = relu(sum_z part_z + b1) -> bf16 ----

__global__ __launch_bounds__(256) void reduce_heads(const short* __restrict__ part,
                                                    const float* __restrict__ b1,
                                                    short* __restrict__ h_bf) {
    int i = blockIdx.x * blockDim.x + threadIdx.x;   // vec8 index over 4M elems
    float s[8] = {0,0,0,0,0,0,0,0};
    #pragma unroll
    for (int z = 0; z < 4; ++z) {
        shortx8 v = ((const shortx8*)(part + (long)z * 4194304))[i];
        #pragma unroll
        for (int e = 0; e < 8; ++e) s[e] += bf2f(v[e]);
    }
    int j0 = (i * 8) & 1023;
    shortx8 o;
    #pragma unroll
    for (int e = 0; e < 8; ++e) o[e] = f2bf(fmaxf(s[e] + b1[j0 + e], 0.f));
    ((shortx8*)h_bf)[i] = o;
}

// ---------------- launch ----------------

extern "C" void kernel_launch(void* const* d_in, const int* in_sizes, int n_in,
                              void* d_out, int out_size, void* d_ws, size_t ws_size,
                              hipStream_t stream) {
    const float* sentences = (const float*)d_in[0];
    const float* knowledge = (const float*)d_in[1];
    const float* mask      = (const float*)d_in[2];
    const float* Ws        = (const float*)d_in[3];
    const float* bs        = (const float*)d_in[4];
    const float* Wk        = (const float*)d_in[5];
    const float* bk        = (const float*)d_in[6];
    const float* W1        = (const float*)d_in[7];
    const float* b1        = (const float*)d_in[8];
    const float* W2        = (const float*)d_in[9];
    const float* b2        = (const float*)d_in[10];

    float* out  = (float*)d_out;
    float* attn = out + 4194304;           // weights region: [8*4096, 4096] fp32

    // ws layout (total ~126 MB):
    char* ws = (char*)d_ws;
    short* V_T     = (short*)(ws);                   // 64 MB  [j][h*4096+m]
    short* W2T     = (short*)(ws + 67108864);        //  2 MB  [j2][j]
    short* h_bf    = (short*)(ws + 69206016);        //  8 MB  [n][j]
    float* bias2   = (float*)(ws + 77594624);        // 16 KB  bs||bk
    short* sent_bf = (short*)(ws + 77611008);        //  8 MB
    short* know_bf = (short*)(ws + 85999616);        //  8 MB
    short* WsT     = (short*)(ws + 94388224);        //  2 MB  [j=h*128+e][d]
    short* WkT     = (short*)(ws + 96485376);        //  2 MB
    short* W1T     = (short*)(ws + 98582528);        // 16 MB  [h][j][d]
    short* S_bf    = (short*)(ws + 115359744);       //  8 MB  [n][h*128+e]
    short* K_bf    = (short*)(ws + 123748352);       //  8 MB  [m][h*128+e] (z=1 of proj)
    short* part    = (short*)(ws + 77611008);        // 32 MB bf16, aliases dead pool
    (void)K_bf;

    // prep: casts + weight transposes + bias pack
    cast_bf16<<<4096, 256, 0, stream>>>(sentences, sent_bf, 1048576);
    cast_bf16<<<4096, 256, 0, stream>>>(knowledge, know_bf, 1048576);
    transpose_cast<<<dim3(4, 32, 8),  dim3(32, 8), 0, stream>>>(Ws, WsT, 1024, 128, 131072, 131072);
    transpose_cast<<<dim3(4, 32, 8),  dim3(32, 8), 0, stream>>>(Wk, WkT, 1024, 128, 131072, 131072);
    transpose_cast<<<dim3(32, 32, 8), dim3(32, 8), 0, stream>>>(W1, W1T, 1024, 1024, 1048576, 1048576);
    transpose_cast<<<dim3(32, 32, 1), dim3(32, 8), 0, stream>>>(W2, W2T, 1024, 1024, 0, 0);
    hipMemcpyAsync(bias2,        bs, 4096, hipMemcpyDeviceToDevice, stream);
    hipMemcpyAsync(bias2 + 1024, bk, 4096, hipMemcpyDeviceToDevice, stream);

    // batched S/K projection: z=0 sentences@Ws+bs -> S_bf, z=1 knowledge@Wk+bk -> K_bf
    gemm_nt<false, false><<<dim3(8, 32, 2), 256, 0, stream>>>(
        sent_bf, WsT, S_bf, bias2, 1.0f, 1024, 1024, 1024, 1024,
        4194304, 1048576, 4194304, 1024);
    // V_T[j][h*4096+m] = (knowledge @ W1_h)[m][j]
    gemm_nt<false, false><<<dim3(32, 8, 8), 256, 0, stream>>>(
        W1T, know_bf, V_T, nullptr, 1.0f, 1024, 1024, 1024, 32768,
        1048576, 0, 4096, 0);
    // raw scores -> d_out weights region (fp32), scaled 1/sqrt(128)
    gemm_nt<false, true><<<dim3(32, 32, 8), 256, 0, stream>>>(
        S_bf, K_bf, attn, nullptr, 0.08838834764831845f, 128, 1024, 1024, 4096,
        128, 128, 16777216, 0);
    // softmax over knowledge dim + post-softmax mask, in place
    softmax_mask<<<32768, 256, 0, stream>>>(attn, mask);
    // big GEMM, split-K over head pairs: part[z] = attn[:, z-pair] @ V_T[z-pair]^T
    gemm_attnv<<<dim3(8, 32, 4), 256, 0, stream>>>(
        attn, V_T, part, 8192, 4096, 32768, 1024,
        33554432, 8192, 4194304, 16777216 - 4096);
    // h = relu(sum_z part_z + b1) -> bf16
    reduce_heads<<<2048, 256, 0, stream>>>(part, b1, h_bf);
    // output = h @ W2 + b2 -> d_out[0:4M] fp32
    gemm_nt<false, true><<<dim3(8, 32, 1), 256, 0, stream>>>(
        h_bf, W2T, out, b2, 1.0f, 1024, 1024, 1024, 1024, 0, 0, 0, 0);
}